// Round 6
// baseline (166.249 us; speedup 1.0000x reference)
//
#include <hip/hip_runtime.h>
#include <hip/hip_cooperative_groups.h>
#include <math.h>

namespace cg = cooperative_groups;

#define H_DIM 2048
#define NUM_V 32
#define DK 128
#define DV 128
#define KSZ 4
#define KEY_DIM 2048
#define VALUE_DIM 4096
#define CONV_DIM 8192

// workspace layout (floats):
#define WS_QKV   0       // 8192
#define WS_Z     8192    // 4096
#define WS_B     12288   // 32
#define WS_A     12320   // 32
#define WS_XN    12352   // 4096 (normed core, pre-gate; coop path)
#define WS_OUT   20544   // 4096 (gated; fallback path)

__device__ __forceinline__ float wave_reduce_sum(float v) {
#pragma unroll
    for (int off = 32; off > 0; off >>= 1) v += __shfl_down(v, off, 64);
    return v;
}

// ============================ cooperative single kernel ============================
// 512 blocks x 256 threads = 2 blocks/CU co-resident (conservative-safe), 2048 waves.
__global__ __launch_bounds__(256, 2) void fused_decode_kernel(
        const float* __restrict__ h,
        const float* __restrict__ conv_state,
        const float* __restrict__ rec_in,
        const float* __restrict__ conv_w,
        const float* __restrict__ qkv_w,
        const float* __restrict__ z_w,
        const float* __restrict__ b_w,
        const float* __restrict__ a_w,
        const float* __restrict__ out_proj_w,
        const float* __restrict__ dt_bias,
        const float* __restrict__ A_log,
        const float* __restrict__ norm_w,
        float* __restrict__ ws,
        float* __restrict__ hidden_out,
        float* __restrict__ new_conv_state,
        float* __restrict__ rec_out) {
    cg::grid_group grid = cg::this_grid();

    const int t = threadIdx.x;
    const int lane = t & 63;
    const int w = t >> 6;                  // wave in block (0..3)
    const int gw = blockIdx.x * 4 + w;     // global wave (0..2047)
    const float4* h4 = (const float4*)h;

    // static LDS total ~22.2 KB; 2 blocks/CU -> 44.4 KB/CU (< even 64 KB budget)
    __shared__ float qc[DK], kc[DK], vc[DV], dl[DV];
    __shared__ float part[8][DV];
    __shared__ float red[4];
    __shared__ float4 out_lds[VALUE_DIM / 4];   // 16 KB

    // ================= P0: qkv + b + a projections (8256 rows) =================
    for (int row = gw; row < CONV_DIM + 2 * NUM_V; row += 2048) {
        const float* rp;
        float* dst;
        if (row < CONV_DIM) {
            rp = qkv_w + (size_t)row * H_DIM;
            dst = ws + WS_QKV + row;
        } else if (row < CONV_DIM + NUM_V) {
            int r = row - CONV_DIM;
            rp = b_w + (size_t)r * H_DIM;
            dst = ws + WS_B + r;
        } else {
            int r = row - CONV_DIM - NUM_V;
            rp = a_w + (size_t)r * H_DIM;
            dst = ws + WS_A + r;
        }
        const float4* r4 = (const float4*)rp;
        float acc = 0.f;
#pragma unroll
        for (int i = 0; i < 8; ++i) {
            float4 w4 = r4[lane + 64 * i];
            float4 hv = h4[lane + 64 * i];
            acc += w4.x * hv.x + w4.y * hv.y + w4.z * hv.z + w4.w * hv.w;
        }
        acc = wave_reduce_sum(acc);
        if (lane == 0) *dst = acc;
    }

    grid.sync();

    // ===== P1: blocks 0..31 = head update; blocks 32..511 = z projection =====
    if (blockIdx.x < 32) {
        const int n = blockIdx.x;
        const int sh = n >> 1;   // shared q/k head (VPK=2)

        // fused causal-conv + silu for this head's q/k/v slices
        for (int idx = t; idx < 384; idx += 256) {
            int slice = idx >> 7;   // 0=q,1=k,2=v
            int j = idx & 127;
            int c;
            if (slice == 0)      c = sh * DK + j;
            else if (slice == 1) c = KEY_DIM + sh * DK + j;
            else                 c = 2 * KEY_DIM + n * DV + j;
            float4 cs = ((const float4*)conv_state)[c];
            float4 cw = ((const float4*)conv_w)[c];
            float mq = ws[WS_QKV + c];
            float pre = cs.y * cw.x + cs.z * cw.y + cs.w * cw.z + mq * cw.w;
            float so = pre / (1.f + expf(-pre));   // silu
            if (slice == 0)      qc[j] = so;
            else if (slice == 1) kc[j] = so;
            else                 vc[j] = so;
            float4 ns; ns.x = cs.y; ns.y = cs.z; ns.z = cs.w; ns.w = mq;
            ((float4*)new_conv_state)[c] = ns;   // q/k double-written identically
        }
        __syncthreads();

        // l2-norms of q and k (wave0 -> q, wave1 -> k)
        if (t < 64) {
            float s = qc[t] * qc[t] + qc[t + 64] * qc[t + 64];
            s = wave_reduce_sum(s);
            if (lane == 0) red[0] = s;
        } else if (t < 128) {
            int j = t - 64;
            float s = kc[j] * kc[j] + kc[j + 64] * kc[j + 64];
            s = wave_reduce_sum(s);
            if (lane == 0) red[1] = s;
        }
        __syncthreads();
        if (t < 128) {
            float qin = rsqrtf(red[0] + 1e-6f) * 0.08838834764831845f; // 1/sqrt(128)
            float kin = rsqrtf(red[1] + 1e-6f);
            qc[t] *= qin;
            kc[t] *= kin;
        }

        // per-head scalars
        float bb = ws[WS_B + n];
        float aa = ws[WS_A + n];
        float beta = 1.f / (1.f + expf(-bb));
        float xx = aa + dt_bias[n];
        float sp = (xx > 20.f) ? xx : log1pf(expf(xx));
        float gexp = expf(-expf(A_log[n]) * sp);
        __syncthreads();

        const float4* rn4 = (const float4*)(rec_in + (size_t)n * DK * DV);
        float4* ro4 = (float4*)(rec_out + (size_t)n * DK * DV);
        const int cgp = t & 31;   // float4 column group
        const int chp = t >> 5;   // k-chunk (0..7), 16 k each

        // pass 1: kv_mem
        {
            float4 kv = {0.f, 0.f, 0.f, 0.f};
#pragma unroll
            for (int j = 0; j < 16; ++j) {
                int k = chp * 16 + j;
                float4 r = rn4[k * 32 + cgp];
                float kk = kc[k];
                kv.x += r.x * kk; kv.y += r.y * kk; kv.z += r.z * kk; kv.w += r.w * kk;
            }
            ((float4*)part[chp])[cgp] = kv;
        }
        __syncthreads();
        if (t < DV) {
            float s = 0.f;
#pragma unroll
            for (int c = 0; c < 8; ++c) s += part[c][t];
            s *= gexp;
            dl[t] = (vc[t] - s) * beta;
        }
        __syncthreads();

        // pass 2: rec' = rec*gexp + k (x) delta ; core = rec'^T q
        {
            float4 d4 = ((const float4*)dl)[cgp];
            float4 core = {0.f, 0.f, 0.f, 0.f};
#pragma unroll
            for (int j = 0; j < 16; ++j) {
                int k = chp * 16 + j;
                float4 r = rn4[k * 32 + cgp];
                float kk = kc[k];
                float qq = qc[k];
                float4 val;
                val.x = r.x * gexp + kk * d4.x;
                val.y = r.y * gexp + kk * d4.y;
                val.z = r.z * gexp + kk * d4.z;
                val.w = r.w * gexp + kk * d4.w;
                ro4[k * 32 + cgp] = val;
                core.x += val.x * qq; core.y += val.y * qq;
                core.z += val.z * qq; core.w += val.w * qq;
            }
            ((float4*)part[chp])[cgp] = core;
        }
        __syncthreads();
        if (t < DV) {
            float c = 0.f;
#pragma unroll
            for (int cc = 0; cc < 8; ++cc) c += part[cc][t];
            float s = wave_reduce_sum(c * c);
            if (lane == 0) red[2 + (t >> 6)] = s;
            vc[t] = c;   // stash core
        }
        __syncthreads();
        if (t < DV) {
            float c = vc[t];
            float var = (red[2] + red[3]) * (1.f / DV);
            ws[WS_XN + n * DV + t] = c * rsqrtf(var + 1e-6f) * norm_w[t];
        }
    } else {
        // z projection: 4096 rows over 480 blocks x 4 waves (grid-stride 1920)
        int zw = (blockIdx.x - 32) * 4 + w;   // 0..1919
        for (int r = zw; r < VALUE_DIM; r += 1920) {
            const float4* r4 = (const float4*)(z_w + (size_t)r * H_DIM);
            float acc = 0.f;
#pragma unroll
            for (int i = 0; i < 8; ++i) {
                float4 w4 = r4[lane + 64 * i];
                float4 hv = h4[lane + 64 * i];
                acc += w4.x * hv.x + w4.y * hv.y + w4.z * hv.z + w4.w * hv.w;
            }
            acc = wave_reduce_sum(acc);
            if (lane == 0) ws[WS_Z + r] = acc;
        }
    }

    grid.sync();

    // ================= P2: gate (xn * silu(z)) into LDS, then out-proj =================
    {
        const float4* xn4 = (const float4*)(ws + WS_XN);
        const float4* z4 = (const float4*)(ws + WS_Z);
        for (int i = t; i < VALUE_DIM / 4; i += 256) {
            float4 x = xn4[i];
            float4 z = z4[i];
            float4 o;
            o.x = x.x * (z.x / (1.f + expf(-z.x)));
            o.y = x.y * (z.y / (1.f + expf(-z.y)));
            o.z = x.z * (z.z / (1.f + expf(-z.z)));
            o.w = x.w * (z.w / (1.f + expf(-z.w)));
            out_lds[i] = o;
        }
    }
    __syncthreads();

    // exactly one row per wave: 512 blocks x 4 waves = 2048 rows
    {
        const int row = gw;
        const float4* r4 = (const float4*)(out_proj_w + (size_t)row * VALUE_DIM);
        float acc = 0.f;
#pragma unroll
        for (int i = 0; i < 16; ++i) {
            float4 w4 = r4[lane + 64 * i];
            float4 ov = out_lds[lane + 64 * i];
            acc += w4.x * ov.x + w4.y * ov.y + w4.z * ov.z + w4.w * ov.w;
        }
        acc = wave_reduce_sum(acc);
        if (lane == 0) hidden_out[row] = acc;
    }
}

// ============================ fallback path (proven, 32.8 us) ============================
__global__ void proj_kernel(const float* __restrict__ h,
                            const float* __restrict__ qkv_w,
                            const float* __restrict__ z_w,
                            const float* __restrict__ b_w,
                            const float* __restrict__ a_w,
                            float* __restrict__ ws) {
    const int R = CONV_DIM + VALUE_DIM + 2 * NUM_V;  // 12352
    int wave = (blockIdx.x * blockDim.x + threadIdx.x) >> 6;
    int lane = threadIdx.x & 63;
    if (wave >= R) return;

    const float* row;
    float* dst;
    if (wave < CONV_DIM) {
        row = qkv_w + (size_t)wave * H_DIM;
        dst = ws + WS_QKV + wave;
    } else if (wave < CONV_DIM + VALUE_DIM) {
        int r = wave - CONV_DIM;
        row = z_w + (size_t)r * H_DIM;
        dst = ws + WS_Z + r;
    } else if (wave < CONV_DIM + VALUE_DIM + NUM_V) {
        int r = wave - CONV_DIM - VALUE_DIM;
        row = b_w + (size_t)r * H_DIM;
        dst = ws + WS_B + r;
    } else {
        int r = wave - CONV_DIM - VALUE_DIM - NUM_V;
        row = a_w + (size_t)r * H_DIM;
        dst = ws + WS_A + r;
    }

    const float4* row4 = (const float4*)row;
    const float4* h4 = (const float4*)h;
    float acc = 0.f;
#pragma unroll
    for (int i = 0; i < 8; ++i) {
        float4 w4 = row4[lane + 64 * i];
        float4 hv = h4[lane + 64 * i];
        acc += w4.x * hv.x + w4.y * hv.y + w4.z * hv.z + w4.w * hv.w;
    }
    acc = wave_reduce_sum(acc);
    if (lane == 0) *dst = acc;
}

__global__ __launch_bounds__(512) void head_kernel(
        const float* __restrict__ conv_state,
        const float* __restrict__ conv_w,
        float* __restrict__ ws,
        const float* __restrict__ rec_in,
        const float* __restrict__ dt_bias,
        const float* __restrict__ A_log,
        const float* __restrict__ norm_w,
        float* __restrict__ new_conv_state,
        float* __restrict__ rec_out) {
    __shared__ float qc[DK];
    __shared__ float kc[DK];
    __shared__ float vc[DV];
    __shared__ float delta_lds[DV];
    __shared__ float part[16][DV];
    __shared__ float red[4];

    const int n = blockIdx.x;
    const int sh = n >> 1;
    const int t = threadIdx.x;
    const int lane = t & 63;

    if (t < 384) {
        int slice = t >> 7;
        int j = t & 127;
        int c;
        if (slice == 0)      c = sh * DK + j;
        else if (slice == 1) c = KEY_DIM + sh * DK + j;
        else                 c = 2 * KEY_DIM + n * DV + j;
        float4 cs = ((const float4*)conv_state)[c];
        float4 w  = ((const float4*)conv_w)[c];
        float mq  = ws[WS_QKV + c];
        float pre = cs.y * w.x + cs.z * w.y + cs.w * w.z + mq * w.w;
        float so  = pre / (1.f + expf(-pre));
        if (slice == 0)      qc[j] = so;
        else if (slice == 1) kc[j] = so;
        else                 vc[j] = so;
        float4 ns; ns.x = cs.y; ns.y = cs.z; ns.z = cs.w; ns.w = mq;
        ((float4*)new_conv_state)[c] = ns;
    }
    __syncthreads();

    if (t < 64) {
        float s = qc[t] * qc[t] + qc[t + 64] * qc[t + 64];
        s = wave_reduce_sum(s);
        if (lane == 0) red[0] = s;
    } else if (t < 128) {
        int j = t - 64;
        float s = kc[j] * kc[j] + kc[j + 64] * kc[j + 64];
        s = wave_reduce_sum(s);
        if (lane == 0) red[1] = s;
    }
    __syncthreads();
    {
        float qin = rsqrtf(red[0] + 1e-6f) * 0.08838834764831845f;
        float kin = rsqrtf(red[1] + 1e-6f);
        if (t < 128) {
            qc[t] *= qin;
            kc[t] *= kin;
        }
    }

    float bb = ws[WS_B + n];
    float aa = ws[WS_A + n];
    float beta = 1.f / (1.f + expf(-bb));
    float x = aa + dt_bias[n];
    float sp = (x > 20.f) ? x : log1pf(expf(x));
    float gexp = expf(-expf(A_log[n]) * sp);
    __syncthreads();

    const float4* rn4 = (const float4*)(rec_in + (size_t)n * DK * DV);
    float4* ro4 = (float4*)(rec_out + (size_t)n * DK * DV);
    const int cg = t & 31;
    const int ch = t >> 5;

    {
        float4 kv = {0.f, 0.f, 0.f, 0.f};
#pragma unroll
        for (int j = 0; j < 8; ++j) {
            int k = ch * 8 + j;
            float4 r = rn4[k * 32 + cg];
            float kk = kc[k];
            kv.x += r.x * kk; kv.y += r.y * kk; kv.z += r.z * kk; kv.w += r.w * kk;
        }
        ((float4*)part[ch])[cg] = kv;
    }
    __syncthreads();
    if (t < DV) {
        float kv = 0.f;
#pragma unroll
        for (int c = 0; c < 16; ++c) kv += part[c][t];
        kv *= gexp;
        delta_lds[t] = (vc[t] - kv) * beta;
    }
    __syncthreads();

    {
        float4 d4 = ((const float4*)delta_lds)[cg];
        float4 core = {0.f, 0.f, 0.f, 0.f};
#pragma unroll
        for (int j = 0; j < 8; ++j) {
            int k = ch * 8 + j;
            float4 r = rn4[k * 32 + cg];
            float kk = kc[k];
            float4 val;
            val.x = r.x * gexp + kk * d4.x;
            val.y = r.y * gexp + kk * d4.y;
            val.z = r.z * gexp + kk * d4.z;
            val.w = r.w * gexp + kk * d4.w;
            ro4[k * 32 + cg] = val;
            float qq = qc[k];
            core.x += val.x * qq; core.y += val.y * qq;
            core.z += val.z * qq; core.w += val.w * qq;
        }
        ((float4*)part[ch])[cg] = core;
    }
    __syncthreads();

    if (t < DV) {
        float core = 0.f;
#pragma unroll
        for (int c = 0; c < 16; ++c) core += part[c][t];
        float s = wave_reduce_sum(core * core);
        if (lane == 0) red[2 + (t >> 6)] = s;
        vc[t] = core;
    }
    __syncthreads();
    if (t < DV) {
        float core = vc[t];
        float var = (red[2] + red[3]) * (1.f / DV);
        float xn = core * rsqrtf(var + 1e-6f) * norm_w[t];
        float zv = ws[WS_Z + n * DV + t];
        float silz = zv / (1.f + expf(-zv));
        ws[WS_OUT + n * DV + t] = xn * silz;
    }
}

__global__ void outproj_kernel(const float* __restrict__ ws,
                               const float* __restrict__ out_proj_w,
                               float* __restrict__ hidden_out) {
    int wave = (blockIdx.x * blockDim.x + threadIdx.x) >> 6;
    int lane = threadIdx.x & 63;
    if (wave >= H_DIM) return;
    const float4* row4 = (const float4*)(out_proj_w + (size_t)wave * VALUE_DIM);
    const float4* o4 = (const float4*)(ws + WS_OUT);
    float acc = 0.f;
#pragma unroll
    for (int i = 0; i < 16; ++i) {
        float4 w4 = row4[lane + 64 * i];
        float4 ov = o4[lane + 64 * i];
        acc += w4.x * ov.x + w4.y * ov.y + w4.z * ov.z + w4.w * ov.w;
    }
    acc = wave_reduce_sum(acc);
    if (lane == 0) hidden_out[wave] = acc;
}

extern "C" void kernel_launch(void* const* d_in, const int* in_sizes, int n_in,
                              void* d_out, int out_size, void* d_ws, size_t ws_size,
                              hipStream_t stream) {
    const float* h          = (const float*)d_in[0];   // (1,1,2048)
    const float* conv_state = (const float*)d_in[1];   // (1,8192,4)
    const float* rec_in     = (const float*)d_in[2];   // (1,32,128,128)
    const float* conv_w     = (const float*)d_in[3];   // (8192,4)
    const float* qkv_w      = (const float*)d_in[4];   // (8192,2048)
    const float* z_w        = (const float*)d_in[5];   // (4096,2048)
    const float* b_w        = (const float*)d_in[6];   // (32,2048)
    const float* a_w        = (const float*)d_in[7];   // (32,2048)
    const float* out_proj_w = (const float*)d_in[8];   // (2048,4096)
    const float* dt_bias    = (const float*)d_in[9];   // (32,)
    const float* A_log      = (const float*)d_in[10];  // (32,)
    const float* norm_w     = (const float*)d_in[11];  // (128,)

    float* out = (float*)d_out;
    float* hidden_out = out;                           // 2048
    float* new_conv   = out + H_DIM;                   // 32768
    float* rec_out    = out + H_DIM + CONV_DIM * KSZ;  // 524288
    float* ws = (float*)d_ws;

    void* args[] = {
        (void*)&h, (void*)&conv_state, (void*)&rec_in, (void*)&conv_w,
        (void*)&qkv_w, (void*)&z_w, (void*)&b_w, (void*)&a_w,
        (void*)&out_proj_w, (void*)&dt_bias, (void*)&A_log, (void*)&norm_w,
        (void*)&ws, (void*)&hidden_out, (void*)&new_conv, (void*)&rec_out
    };
    hipError_t err = hipLaunchCooperativeKernel((const void*)fused_decode_kernel,
                                                dim3(512), dim3(256), args, 0, stream);
    if (err != hipSuccess) {
        (void)hipGetLastError();  // clear sticky error; deterministic fallback
        proj_kernel<<<3088, 256, 0, stream>>>(h, qkv_w, z_w, b_w, a_w, ws);
        head_kernel<<<32, 512, 0, stream>>>(conv_state, conv_w, ws, rec_in,
                                            dt_bias, A_log, norm_w, new_conv, rec_out);
        outproj_kernel<<<512, 256, 0, stream>>>(ws, out_proj_w, hidden_out);
    }
}